// Round 10
// baseline (1138.405 us; speedup 1.0000x reference)
//
#include <hip/hip_runtime.h>
#include <cstdint>
#include <cstddef>

typedef __bf16 bf16;
typedef __bf16 bf16x8 __attribute__((ext_vector_type(8)));
typedef float  f32x4  __attribute__((ext_vector_type(4)));

#define DEVINL static __device__ __forceinline__

DEVINL void gl2lds16(const void* g, void* l) {
  __builtin_amdgcn_global_load_lds((__attribute__((address_space(1))) void*)g,
                                   (__attribute__((address_space(3))) void*)l,
                                   16, 0, 0);
}

DEVINL float loadf(const void* p, size_t i, int isf) {
  return isf ? ((const float*)p)[i] : (float)((const bf16*)p)[i];
}

// fast exact gelu_tanh: x*sigmoid(2u), u = 0.79788456*(x+0.044715x^3)
DEVINL float gelu_fast(float x) {
  float u = 0.7978845608028654f * (x + 0.044715f * x * x * x);
  float s = 1.f / (1.f + __expf(-2.f * u));
  return x * s;
}

// ---------------- BigBird connectivity table (host MT19937 == numpy RandomState(0)) ----------------
struct TabArg { unsigned char idx[62][8]; unsigned char cnt[62]; };

struct HostMT {
  unsigned mt[624]; int mti;
  void seed(unsigned s) {
    mt[0] = s;
    for (int i = 1; i < 624; ++i) mt[i] = 1812433253u * (mt[i-1] ^ (mt[i-1] >> 30)) + (unsigned)i;
    mti = 624;
  }
  unsigned next() {
    if (mti == 624) {
      for (int i = 0; i < 624; ++i) {
        unsigned y = (mt[i] & 0x80000000u) | (mt[(i+1)%624] & 0x7fffffffu);
        unsigned v = mt[(i+397)%624] ^ (y >> 1);
        if (y & 1u) v ^= 0x9908b0dfu;
        mt[i] = v;
      }
      mti = 0;
    }
    unsigned y = mt[mti++];
    y ^= y >> 11; y ^= (y << 7) & 0x9d2c5680u; y ^= (y << 15) & 0xefc60000u; y ^= y >> 18;
    return y;
  }
  unsigned interval(unsigned mx) {
    if (mx == 0) return 0;
    unsigned mask = mx;
    mask |= mask>>1; mask |= mask>>2; mask |= mask>>4; mask |= mask>>8; mask |= mask>>16;
    unsigned v = next() & mask;
    while (v > mx) v = next() & mask;
    return v;
  }
};

static void build_tab(TabArg* t) {
  HostMT rng; rng.seed(0u);
  for (int row = 0; row < 62; ++row) {
    int i = row + 1;
    bool fix[64] = {};
    fix[0] = true; fix[63] = true; fix[i-1] = true; fix[i] = true; fix[i+1] = true;
    int fixed[5]; int nf = 0; int allowed[64]; int na = 0;
    for (int b = 0; b < 64; ++b) { if (fix[b]) fixed[nf++] = b; else allowed[na++] = b; }
    int perm[64];
    for (int j = 0; j < na; ++j) perm[j] = j;
    for (int j = na - 1; j > 0; --j) {
      unsigned kk = rng.interval((unsigned)j);
      int tmp = perm[j]; perm[j] = perm[kk]; perm[kk] = tmp;
    }
    int nb = 0;
    for (int j = 0; j < nf; ++j) t->idx[row][nb++] = (unsigned char)fixed[j];
    for (int j = 0; j < 3;  ++j) t->idx[row][nb++] = (unsigned char)allowed[perm[j]];
    t->cnt[row] = (unsigned char)nb;
    for (int j = nb; j < 8; ++j) t->idx[row][j] = 0;
  }
}

// ---------------- dtype detection ----------------
__global__ __launch_bounds__(256) void detect_kernel(const unsigned short* __restrict__ x,
                                                     int* __restrict__ flag) {
  __shared__ int cnt[256];
  int c = 0;
  for (int i = threadIdx.x; i < 8192; i += 256) {
    int e = (x[i] >> 7) & 0xFF;
    if (e >= 0xC6) c++;
  }
  cnt[threadIdx.x] = c;
  __syncthreads();
  for (int s = 128; s > 0; s >>= 1) {
    if (threadIdx.x < s) cnt[threadIdx.x] += cnt[threadIdx.x + s];
    __syncthreads();
  }
  if (threadIdx.x == 0) *flag = (cnt[0] > 32) ? 1 : 0;
}

// ---------------- convert 6 small param arrays in one dispatch ----------------
struct P6 { const void* s[6]; bf16* d[6]; int n[6]; };
__global__ __launch_bounds__(256) void cvt6_kernel(const int* __restrict__ flagp, P6 p) {
  int isf = *flagp;
  int which = blockIdx.x;
  const void* src = p.s[which];
  bf16* dst = p.d[which];
  int n = p.n[which];
  int i8 = threadIdx.x * 8;
  if (i8 >= n) return;
  bf16x8 o;
  if (isf) {
    const float* s = (const float*)src + i8;
    f32x4 a = *(const f32x4*)s;
    f32x4 b = *(const f32x4*)(s + 4);
#pragma unroll
    for (int j = 0; j < 4; ++j) { o[j] = (bf16)a[j]; o[4+j] = (bf16)b[j]; }
  } else {
    o = *(const bf16x8*)((const bf16*)src + i8);
  }
  *(bf16x8*)(dst + i8) = o;
}

// ---------------- all 6 weights: fused convert + 64x64 transpose in ONE dispatch ----------------
struct W6 { const void* in[6]; bf16* out[6]; int R[6], C[6], start[6]; };
__global__ __launch_bounds__(256) void transpose_w6_kernel(const int* __restrict__ flagp, W6 wz) {
  __shared__ __align__(16) bf16 sT[64 * 72];
  int isf = *flagp;
  int which = 0;
#pragma unroll
  for (int i = 1; i < 6; ++i) if ((int)blockIdx.x >= wz.start[i]) which = i;
  const void* in = wz.in[which];
  bf16* out = wz.out[which];
  int R = wz.R[which], C = wz.C[which];
  int bid = blockIdx.x - wz.start[which];
  int cb = C >> 6;
  int br = bid / cb, bc = bid % cb;
  int r0 = br * 64, c0 = bc * 64;
  int t = threadIdx.x;
#pragma unroll
  for (int p = 0; p < 2; ++p) {
    int cid = p * 256 + t;
    int r = cid >> 3, c = cid & 7;
    bf16x8 v;
    if (isf) {
      const float* s = (const float*)in + (size_t)(r0 + r) * C + c0 + c * 8;
      f32x4 a = *(const f32x4*)s;
      f32x4 b = *(const f32x4*)(s + 4);
#pragma unroll
      for (int j = 0; j < 4; ++j) { v[j] = (bf16)a[j]; v[4+j] = (bf16)b[j]; }
    } else {
      v = *(const bf16x8*)((const bf16*)in + (size_t)(r0 + r) * C + c0 + c * 8);
    }
    *(bf16x8*)&sT[r * 72 + c * 8] = v;
  }
  __syncthreads();
#pragma unroll
  for (int p = 0; p < 2; ++p) {
    int cid = p * 256 + t;
    int oc = cid >> 3, rc = cid & 7;
    bf16x8 vv;
#pragma unroll
    for (int i = 0; i < 8; ++i) vv[i] = sT[(rc * 8 + i) * 72 + oc];
    *(bf16x8*)&out[(size_t)(c0 + oc) * R + r0 + rc * 8] = vv;
  }
}

// ---------------- LayerNorm over raw (flag-dispatched) input ----------------
__global__ __launch_bounds__(256) void ln_any_kernel(const int* __restrict__ flagp,
                                                     const void* __restrict__ x,
                                                     const bf16* __restrict__ sc,
                                                     const bf16* __restrict__ bi,
                                                     bf16* __restrict__ out) {
  int isf = *flagp;
  int row  = blockIdx.x * 4 + (threadIdx.x >> 6);
  int lane = threadIdx.x & 63;
  float f[8];
  if (isf) {
    const float* xf = (const float*)x + (size_t)row * 512 + lane * 8;
    f32x4 a = *(const f32x4*)xf;
    f32x4 b = *(const f32x4*)(xf + 4);
#pragma unroll
    for (int j = 0; j < 4; ++j) { f[j] = a[j]; f[4+j] = b[j]; }
  } else {
    bf16x8 v = ((const bf16x8*)((const bf16*)x + (size_t)row * 512))[lane];
#pragma unroll
    for (int j = 0; j < 8; ++j) f[j] = (float)v[j];
  }
  float s = 0.f, s2 = 0.f;
#pragma unroll
  for (int i = 0; i < 8; ++i) { s += f[i]; s2 += f[i]*f[i]; }
#pragma unroll
  for (int o = 32; o > 0; o >>= 1) { s += __shfl_xor(s, o, 64); s2 += __shfl_xor(s2, o, 64); }
  float mu  = s  * (1.f/512.f);
  float var = s2 * (1.f/512.f) - mu*mu;
  float rs  = rsqrtf(fmaxf(var, 0.f) + 1e-6f);
  bf16x8 sv = ((const bf16x8*)sc)[lane];
  bf16x8 bv = ((const bf16x8*)bi)[lane];
  bf16x8 o8;
#pragma unroll
  for (int i = 0; i < 8; ++i) o8[i] = (bf16)((f[i]-mu)*rs*(float)sv[i] + (float)bv[i]);
  ((bf16x8*)(out + (size_t)row * 512))[lane] = o8;
}

// ---------------- LayerNorm (bf16) ----------------
__global__ __launch_bounds__(256) void ln_bf16_kernel(const bf16* __restrict__ x,
                                                      const bf16* __restrict__ sc,
                                                      const bf16* __restrict__ bi,
                                                      bf16* __restrict__ out) {
  int row  = blockIdx.x * 4 + (threadIdx.x >> 6);
  int lane = threadIdx.x & 63;
  bf16x8 v = ((const bf16x8*)(x + (size_t)row * 512))[lane];
  float f[8], s = 0.f, s2 = 0.f;
#pragma unroll
  for (int i = 0; i < 8; ++i) { f[i] = (float)v[i]; s += f[i]; s2 += f[i]*f[i]; }
#pragma unroll
  for (int o = 32; o > 0; o >>= 1) { s += __shfl_xor(s, o, 64); s2 += __shfl_xor(s2, o, 64); }
  float mu  = s  * (1.f/512.f);
  float var = s2 * (1.f/512.f) - mu*mu;
  float rs  = rsqrtf(fmaxf(var, 0.f) + 1e-6f);
  bf16x8 sv = ((const bf16x8*)sc)[lane];
  bf16x8 bv = ((const bf16x8*)bi)[lane];
  bf16x8 o8;
#pragma unroll
  for (int i = 0; i < 8; ++i) o8[i] = (bf16)((f[i]-mu)*rs*(float)sv[i] + (float)bv[i]);
  ((bf16x8*)(out + (size_t)row * 512))[lane] = o8;
}

// ---------------- v [b,s,h,dh] -> vT [b,h,dh,s] ----------------
__global__ __launch_bounds__(256) void transpose_v_kernel(const bf16* __restrict__ v,
                                                          bf16* __restrict__ vT) {
  __shared__ __align__(16) bf16 sT[64 * 72];
  int st = blockIdx.x & 63;
  int h  = (blockIdx.x >> 6) & 7;
  int b  = blockIdx.x >> 9;
  int s0 = st * 64;
  int t  = threadIdx.x;
  const size_t ibase = ((size_t)b * 4096) * 512 + h * 64;
#pragma unroll
  for (int p = 0; p < 2; ++p) {
    int cid = p * 256 + t;
    int r = cid >> 3, c = cid & 7;
    *(bf16x8*)&sT[r * 72 + c * 8] = *(const bf16x8*)&v[ibase + (size_t)(s0 + r) * 512 + c * 8];
  }
  __syncthreads();
  const size_t obase = ((size_t)(b * 8 + h) * 64) * 4096;
#pragma unroll
  for (int p = 0; p < 2; ++p) {
    int cid = p * 256 + t;
    int dh = cid >> 3, scn = cid & 7;
    bf16x8 vv;
#pragma unroll
    for (int i = 0; i < 8; ++i) vv[i] = sT[(scn * 8 + i) * 72 + dh];
    *(bf16x8*)&vT[obase + (size_t)dh * 4096 + s0 + scn * 8] = vv;
  }
}

// ---------------- A-resident GEMM: one block (512 thr = 8 waves) per 64-row m-strip ----------------
// A[64 x K] staged to LDS in 512-col chunks (once for K=512); B fragments streamed
// from global/L2 per MFMA (no LDS, no steady-state barriers). Waves: wm=w&3 (16-row
// tile), wn=w>>2 (64-col half of each 128-col n-group).
// epi 1: bf16 gout = acc + resid(f32|bf16 per flag)
// epi 2: bf16 gout = gelu_fast(acc + bias)
// epi 3: (f32|bf16 per flag) gout[gout_off+i] = acc + bias + resid(bf16)  [K=2048 path]
// epi 5: QKV split: col<512 -> gout (x0.125), <1024 -> out2, else out3; all [row][512]
__global__ __launch_bounds__(512) void gemmA_kernel(const bf16* __restrict__ A,
                                                    const bf16* __restrict__ BT,
                                                    int N, int K, int epi,
                                                    const bf16* __restrict__ bias,
                                                    const void* __restrict__ resid,
                                                    void* __restrict__ gout,
                                                    bf16* __restrict__ out2,
                                                    bf16* __restrict__ out3,
                                                    size_t gout_off,
                                                    const int* __restrict__ flagp) {
  __shared__ __align__(16) bf16 sA[64 * 512];
  const int t = threadIdx.x;
  const int w = t >> 6, l = t & 63, quad = l >> 4, l15 = l & 15;
  const int wm = w & 3, wn = w >> 2;     // 8 waves: 4 row-tiles x 2 col-halves
  const int m0 = blockIdx.x * 64;
  const int isf = (epi == 1 || epi == 3) ? *flagp : 0;
  const int rr = wm * 16 + l15;           // A-fragment row within strip

  auto stage = [&](int kc) {
#pragma unroll
    for (int p = 0; p < 8; ++p) {
      int cid = p * 512 + t;              // 0..4095
      int r = cid >> 6, c = cid & 63;     // r wave-uniform (p*8+w), c = lane
      int sc = c ^ (r & 7);               // swizzle low 3 bits of chunk index
      gl2lds16(A + (size_t)(m0 + r) * K + kc * 512 + sc * 8, (char*)sA + cid * 16);
    }
  };

  auto compute_group = [&](int g, int kc, f32x4* acc) {
    const int n0g = g * 128 + wn * 64;
    const bf16* bp = BT + (size_t)(n0g + l15) * K + (size_t)kc * 512 + quad * 8;
#pragma unroll
    for (int ks = 0; ks < 16; ++ks) {
      int kidx = ks * 4 + quad;
      bf16x8 af = *(const bf16x8*)&sA[rr * 512 + ((kidx ^ (rr & 7)) << 3)];
#pragma unroll
      for (int nt = 0; nt < 4; ++nt) {
        bf16x8 bf = *(const bf16x8*)(bp + (size_t)nt * 16 * K + ks * 32);
        acc[nt] = __builtin_amdgcn_mfma_f32_16x16x32_bf16(af, bf, acc[nt], 0, 0, 0);
      }
    }
  };

  auto store_group = [&](int g, f32x4* acc) {
    const int n0g = g * 128 + wn * 64;
    const int rowb = m0 + wm * 16 + quad * 4;
#pragma unroll
    for (int nt = 0; nt < 4; ++nt) {
      int col = n0g + nt * 16 + l15;
#pragma unroll
      for (int r = 0; r < 4; ++r) {
        int row = rowb + r;
        float v = acc[nt][r];
        size_t oidx = (size_t)row * N + col;
        if (epi == 5) {
          int which = col >> 9, c2 = col & 511;
          bf16 ov = (bf16)(which == 0 ? v * 0.125f : v);
          bf16* dst = which == 0 ? (bf16*)gout : (which == 1 ? out2 : out3);
          dst[(size_t)row * 512 + c2] = ov;
        } else if (epi == 1) {
          ((bf16*)gout)[oidx] = (bf16)(v + loadf(resid, oidx, isf));
        } else if (epi == 2) {
          ((bf16*)gout)[oidx] = (bf16)gelu_fast(v + (float)bias[col]);
        } else {
          float ov = v + (float)bias[col] + (float)((const bf16*)resid)[oidx];
          if (isf) ((float*)gout)[gout_off + oidx] = ov;
          else     ((bf16*)gout)[gout_off + oidx] = (bf16)ov;
        }
      }
    }
  };

  if (epi != 3) {                          // K == 512: stage once, stream n-groups
    stage(0);
    __syncthreads();
    const int ng = N >> 7;
    for (int g = 0; g < ng; ++g) {
      f32x4 acc[4] = {};
      compute_group(g, 0, acc);
      store_group(g, acc);
    }
  } else {                                 // FFN2: K=2048, N=512, all-N accumulator
    f32x4 accA[4][4] = {};
    const int nkc = K >> 9;
    for (int kc = 0; kc < nkc; ++kc) {
      __syncthreads();                     // readers of previous chunk done
      stage(kc);
      __syncthreads();                     // staging visible
#pragma unroll
      for (int g = 0; g < 4; ++g) compute_group(g, kc, accA[g]);
    }
#pragma unroll
    for (int g = 0; g < 4; ++g) store_group(g, accA[g]);
  }
}

// ---------------- BigBird flash attention, wave-local softmax ----------------
__global__ __launch_bounds__(256) void attn_kernel(TabArg targ,
                                                   const bf16* __restrict__ q,
                                                   const bf16* __restrict__ k,
                                                   const bf16* __restrict__ vT,
                                                   bf16* __restrict__ o,
                                                   float* __restrict__ part,
                                                   int mode) {
  __shared__ __align__(16) bf16 sQ[64 * 64];
  __shared__ __align__(16) bf16 sK[64 * 64];
  __shared__ __align__(16) bf16 sV[64 * 64];
  __shared__ __align__(16) bf16 sP[64 * 64];

  const int t = threadIdx.x;
  const int w = t >> 6, l = t & 63, quad = l >> 4, l15 = l & 15;
  int n, bh, chunk = 0, niter;
  if (mode == 0) {
    int xcd = blockIdx.x & 7, g = blockIdx.x >> 3;
    int bhloc = g / 62;
    n  = 1 + g % 62;
    bh = xcd + bhloc * 8;
    niter = (int)targ.cnt[n - 1];
  } else {
    chunk = blockIdx.x & 7;
    int g = (blockIdx.x >> 3) & 1;
    bh = blockIdx.x >> 4;
    n = g ? 63 : 0;
    niter = 8;
  }
  const int b = bh >> 3, h = bh & 7;
  const size_t bh_qk = ((size_t)b * 4096) * 512 + h * 64;
  const size_t bh_v  = ((size_t)(b * 8 + h) * 64) * 4096;

#pragma unroll
  for (int p = 0; p < 2; ++p) {
    int cid = p * 256 + t;
    int r = cid >> 3, c = cid & 7;
    int sc_ = c ^ (r & 7);
    gl2lds16(q + bh_qk + (size_t)(n * 64 + r) * 512 + sc_ * 8, (char*)sQ + cid * 16);
  }

  float m_r[4], l_r[4];
#pragma unroll
  for (int r = 0; r < 4; ++r) { m_r[r] = -1e30f; l_r[r] = 0.f; }
  f32x4 accO[4] = {};

  for (int it = 0; it < niter; ++it) {
    int kb = (mode == 0) ? (int)targ.idx[n - 1][it] : chunk * 8 + it;
    __syncthreads();
#pragma unroll
    for (int p = 0; p < 2; ++p) {
      int cid = p * 256 + t;
      int r = cid >> 3, c = cid & 7;
      int sc_ = c ^ (r & 7);
      gl2lds16(k  + bh_qk + (size_t)(kb * 64 + r) * 512 + sc_ * 8, (char*)sK + cid * 16);
      gl2lds16(vT + bh_v  + (size_t)r * 4096 + kb * 64 + sc_ * 8,  (char*)sV + cid * 16);
    }
    __syncthreads();

    f32x4 accS[4] = {};
#pragma unroll
    for (int ks = 0; ks < 2; ++ks) {
      int rQ = w * 16 + l15;
      int cc = ks * 4 + quad;
      bf16x8 afr = *(const bf16x8*)&sQ[rQ * 64 + ((cc ^ (rQ & 7)) << 3)];
#pragma unroll
      for (int j = 0; j < 4; ++j) {
        int rK = j * 16 + l15;
        bf16x8 bfr = *(const bf16x8*)&sK[rK * 64 + ((cc ^ (rK & 7)) << 3)];
        accS[j] = __builtin_amdgcn_mfma_f32_16x16x32_bf16(afr, bfr, accS[j], 0, 0, 0);
      }
    }

    float al[4];
#pragma unroll
    for (int r = 0; r < 4; ++r) {
      float mx = fmaxf(fmaxf(accS[0][r], accS[1][r]), fmaxf(accS[2][r], accS[3][r]));
#pragma unroll
      for (int off = 1; off < 16; off <<= 1) mx = fmaxf(mx, __shfl_xor(mx, off, 64));
      float mnew = fmaxf(m_r[r], mx);
      al[r] = __expf(m_r[r] - mnew);
      m_r[r] = mnew;
      int rowp = w * 16 + quad * 4 + r;
      float ps = 0.f;
#pragma unroll
      for (int j = 0; j < 4; ++j) {
        float pv = __expf(accS[j][r] - mnew);
        ps += pv;
        int col = j * 16 + l15;
        sP[rowp * 64 + (((col >> 3) ^ (rowp & 7)) << 3) + (col & 7)] = (bf16)pv;
      }
#pragma unroll
      for (int off = 1; off < 16; off <<= 1) ps += __shfl_xor(ps, off, 64);
      l_r[r] = l_r[r] * al[r] + ps;
    }

#pragma unroll
    for (int dt = 0; dt < 4; ++dt)
#pragma unroll
      for (int r = 0; r < 4; ++r) accO[dt][r] *= al[r];
#pragma unroll
    for (int ks = 0; ks < 2; ++ks) {
      int rP = w * 16 + l15;
      int cc = ks * 4 + quad;
      bf16x8 afr = *(const bf16x8*)&sP[rP * 64 + ((cc ^ (rP & 7)) << 3)];
#pragma unroll
      for (int dt = 0; dt < 4; ++dt) {
        int rV = dt * 16 + l15;
        bf16x8 bfr = *(const bf16x8*)&sV[rV * 64 + ((cc ^ (rV & 7)) << 3)];
        accO[dt] = __builtin_amdgcn_mfma_f32_16x16x32_bf16(afr, bfr, accO[dt], 0, 0, 0);
      }
    }
  }

  if (mode == 0) {
#pragma unroll
    for (int r = 0; r < 4; ++r) {
      int qr = w * 16 + quad * 4 + r;
      float linv = 1.f / fmaxf(l_r[r], 1e-30f);
      int srow = n * 64 + qr;
#pragma unroll
      for (int dt = 0; dt < 4; ++dt)
        o[bh_qk + (size_t)srow * 512 + dt * 16 + l15] = (bf16)(accO[dt][r] * linv);
    }
  } else {
    float* pb = part + (size_t)blockIdx.x * (4096 + 128);
#pragma unroll
    for (int r = 0; r < 4; ++r) {
      int row = w * 16 + quad * 4 + r;
#pragma unroll
      for (int dt = 0; dt < 4; ++dt)
        pb[row * 64 + dt * 16 + l15] = accO[dt][r];
      if (l15 == 0) { pb[4096 + row] = m_r[r]; pb[4160 + row] = l_r[r]; }
    }
  }
}

// ---------------- merge 8 global-attention partials per (b,h,g) ----------------
__global__ __launch_bounds__(256) void merge_kernel(const float* __restrict__ part,
                                                    bf16* __restrict__ o) {
  const int SP = 4096 + 128;
  int g = blockIdx.x & 1, bh = blockIdx.x >> 1;
  int b = bh >> 3, h = bh & 7, n = g ? 63 : 0;
  int t = threadIdx.x;
  int row = t >> 2, st = t & 3;
  size_t pb0 = (size_t)(bh * 16 + g * 8) * SP;
  float mc[8], lc[8], M = -1e30f;
#pragma unroll
  for (int c = 0; c < 8; ++c) {
    mc[c] = part[pb0 + (size_t)c * SP + 4096 + row];
    lc[c] = part[pb0 + (size_t)c * SP + 4160 + row];
    M = fmaxf(M, mc[c]);
  }
  float L = 0.f;
  float sc[8];
#pragma unroll
  for (int c = 0; c < 8; ++c) { sc[c] = __expf(mc[c] - M); L += lc[c] * sc[c]; }
  float inv = 1.f / fmaxf(L, 1e-30f);
  f32x4 acc[4] = {};
#pragma unroll
  for (int c = 0; c < 8; ++c) {
    const float* Op = part + pb0 + (size_t)c * SP + row * 64 + st * 16;
    float s = sc[c];
#pragma unroll
    for (int i = 0; i < 4; ++i) {
      f32x4 v = *(const f32x4*)(Op + i * 4);
#pragma unroll
      for (int j = 0; j < 4; ++j) acc[i][j] += v[j] * s;
    }
  }
  size_t obase = ((size_t)b * 4096 + n * 64 + row) * 512 + h * 64 + st * 16;
#pragma unroll
  for (int i = 0; i < 4; ++i)
#pragma unroll
    for (int j = 0; j < 4; ++j)
      o[obase + i * 4 + j] = (bf16)(acc[i][j] * inv);
}

// ---------------- launch ----------------
extern "C" void kernel_launch(void* const* d_in, const int* in_sizes, int n_in,
                              void* d_out, int out_size, void* d_ws, size_t ws_size,
                              hipStream_t stream) {
  (void)in_sizes; (void)n_in; (void)out_size;
  const void* inputs = d_in[0];
  const void* ln1s = d_in[1];
  const void* ln1b = d_in[2];
  const void* wq   = d_in[3];
  const void* wk   = d_in[4];
  const void* wv   = d_in[5];
  const void* wo   = d_in[6];
  const void* ln2s = d_in[7];
  const void* ln2b = d_in[8];
  const void* w1   = d_in[9];
  const void* b1   = d_in[10];
  const void* w2   = d_in[11];
  const void* b2   = d_in[12];

  TabArg tab;
  build_tab(&tab);

  char* ws = (char*)d_ws;
  size_t off = 0;
  auto alloc = [&](size_t bytes) -> char* {
    char* p = ws + off; off += (bytes + 255) & ~(size_t)255; return p;
  };
  int*  flag   = (int*)alloc(256);
  bf16* ln1s_c = (bf16*)alloc(512 * 2);
  bf16* ln1b_c = (bf16*)alloc(512 * 2);
  bf16* ln2s_c = (bf16*)alloc(512 * 2);
  bf16* ln2b_c = (bf16*)alloc(512 * 2);
  bf16* b1_c   = (bf16*)alloc(2048 * 2);
  bf16* b2_c   = (bf16*)alloc(512 * 2);
  bf16* wqkvT  = (bf16*)alloc(1536ull * 512 * 2);
  bf16* woT    = (bf16*)alloc(512ull * 512 * 2);
  bf16* w1T    = (bf16*)alloc(512ull * 2048 * 2);
  bf16* w2T    = (bf16*)alloc(2048ull * 512 * 2);
  const size_t SZ = 16384ull * 512 * 2;
  bf16* regA = (bf16*)alloc(SZ);   // xln -> vT -> xbuf
  bf16* regB = (bf16*)alloc(SZ);   // qb  -> yln
  bf16* regC = (bf16*)alloc(SZ);   // kb  -> h1 chunk
  bf16* regD = (bf16*)alloc(SZ);   // vb  -> obuf
  size_t base_need = off;
  const size_t H1_BYTES = 16384ull * 2048 * 2;
  bool full_ffn = (ws_size >= base_need + H1_BYTES + 256);
  bf16* h1f = full_ffn ? (bf16*)alloc(H1_BYTES) : nullptr;

  bf16* xln  = regA;
  bf16* qb   = regB;
  bf16* kb   = regC;
  bf16* vb   = regD;
  bf16* vTb  = regA;
  bf16* obuf = regD;
  bf16* xbuf = regA;
  bf16* yln  = regB;
  bf16* h1c  = regC;
  float* part = (float*)d_out;   // d_out is free scratch until FFN2 writes it

  detect_kernel<<<1, 256, 0, stream>>>((const unsigned short*)inputs, flag);

  P6 p6;
  p6.s[0]=ln1s; p6.s[1]=ln1b; p6.s[2]=ln2s; p6.s[3]=ln2b; p6.s[4]=b1; p6.s[5]=b2;
  p6.d[0]=ln1s_c; p6.d[1]=ln1b_c; p6.d[2]=ln2s_c; p6.d[3]=ln2b_c; p6.d[4]=b1_c; p6.d[5]=b2_c;
  p6.n[0]=512; p6.n[1]=512; p6.n[2]=512; p6.n[3]=512; p6.n[4]=2048; p6.n[5]=512;
  cvt6_kernel<<<6, 256, 0, stream>>>(flag, p6);

  W6 w6;
  w6.in[0]=wq; w6.in[1]=wk; w6.in[2]=wv; w6.in[3]=wo; w6.in[4]=w1; w6.in[5]=w2;
  w6.out[0]=wqkvT; w6.out[1]=wqkvT+512ull*512; w6.out[2]=wqkvT+1024ull*512;
  w6.out[3]=woT; w6.out[4]=w1T; w6.out[5]=w2T;
  w6.R[0]=512; w6.R[1]=512; w6.R[2]=512; w6.R[3]=512; w6.R[4]=512;  w6.R[5]=2048;
  w6.C[0]=512; w6.C[1]=512; w6.C[2]=512; w6.C[3]=512; w6.C[4]=2048; w6.C[5]=512;
  w6.start[0]=0; w6.start[1]=64; w6.start[2]=128; w6.start[3]=192; w6.start[4]=256; w6.start[5]=512;
  transpose_w6_kernel<<<768, 256, 0, stream>>>(flag, w6);

  ln_any_kernel<<<4096, 256, 0, stream>>>(flag, inputs, ln1s_c, ln1b_c, xln);

  // fused QKV: N=1536, K=512
  gemmA_kernel<<<256, 512, 0, stream>>>(xln, wqkvT, 1536, 512, 5,
                                        nullptr, nullptr, qb, kb, vb, 0, flag);

  transpose_v_kernel<<<2048, 256, 0, stream>>>(vb, vTb);

  attn_kernel<<<1984, 256, 0, stream>>>(tab, qb, kb, vTb, obuf, part, 0);
  attn_kernel<<<512,  256, 0, stream>>>(tab, qb, kb, vTb, obuf, part, 1);
  merge_kernel<<<64,  256, 0, stream>>>(part, obuf);

  // WO + residual
  gemmA_kernel<<<256, 512, 0, stream>>>(obuf, woT, 512, 512, 1,
                                        nullptr, inputs, xbuf, nullptr, nullptr, 0, flag);

  ln_bf16_kernel<<<4096, 256, 0, stream>>>(xbuf, ln2s_c, ln2b_c, yln);

  if (full_ffn) {
    gemmA_kernel<<<256, 512, 0, stream>>>(yln, w1T, 2048, 512, 2,
                                          b1_c, nullptr, h1f, nullptr, nullptr, 0, flag);
    gemmA_kernel<<<256, 512, 0, stream>>>(h1f, w2T, 512, 2048, 3,
                                          b2_c, xbuf, d_out, nullptr, nullptr, 0, flag);
  } else {
    for (int c = 0; c < 4; ++c) {
      const bf16* yc = yln  + (size_t)c * 4096 * 512;
      const bf16* xc = xbuf + (size_t)c * 4096 * 512;
      size_t oo = (size_t)c * 4096 * 512;
      gemmA_kernel<<<64, 512, 0, stream>>>(yc, w1T, 2048, 512, 2,
                                           b1_c, nullptr, h1c, nullptr, nullptr, 0, flag);
      gemmA_kernel<<<64, 512, 0, stream>>>(h1c, w2T, 512, 2048, 3,
                                           b2_c, xc, d_out, nullptr, nullptr, oo, flag);
    }
  }
}

// Round 11
// 448.265 us; speedup vs baseline: 2.5396x; 2.5396x over previous
//
#include <hip/hip_runtime.h>
#include <cstdint>
#include <cstddef>

typedef __bf16 bf16;
typedef __bf16 bf16x8 __attribute__((ext_vector_type(8)));
typedef float  f32x4  __attribute__((ext_vector_type(4)));

#define DEVINL static __device__ __forceinline__

DEVINL void gl2lds16(const void* g, void* l) {
  __builtin_amdgcn_global_load_lds((__attribute__((address_space(1))) void*)g,
                                   (__attribute__((address_space(3))) void*)l,
                                   16, 0, 0);
}

DEVINL float loadf(const void* p, size_t i, int isf) {
  return isf ? ((const float*)p)[i] : (float)((const bf16*)p)[i];
}

// fast exact gelu_tanh: x*sigmoid(2u), u = 0.79788456*(x+0.044715x^3)
DEVINL float gelu_fast(float x) {
  float u = 0.7978845608028654f * (x + 0.044715f * x * x * x);
  float s = 1.f / (1.f + __expf(-2.f * u));
  return x * s;
}

// ---------------- BigBird connectivity table (host MT19937 == numpy RandomState(0)) ----------------
struct TabArg { unsigned char idx[62][8]; unsigned char cnt[62]; };

struct HostMT {
  unsigned mt[624]; int mti;
  void seed(unsigned s) {
    mt[0] = s;
    for (int i = 1; i < 624; ++i) mt[i] = 1812433253u * (mt[i-1] ^ (mt[i-1] >> 30)) + (unsigned)i;
    mti = 624;
  }
  unsigned next() {
    if (mti == 624) {
      for (int i = 0; i < 624; ++i) {
        unsigned y = (mt[i] & 0x80000000u) | (mt[(i+1)%624] & 0x7fffffffu);
        unsigned v = mt[(i+397)%624] ^ (y >> 1);
        if (y & 1u) v ^= 0x9908b0dfu;
        mt[i] = v;
      }
      mti = 0;
    }
    unsigned y = mt[mti++];
    y ^= y >> 11; y ^= (y << 7) & 0x9d2c5680u; y ^= (y << 15) & 0xefc60000u; y ^= y >> 18;
    return y;
  }
  unsigned interval(unsigned mx) {
    if (mx == 0) return 0;
    unsigned mask = mx;
    mask |= mask>>1; mask |= mask>>2; mask |= mask>>4; mask |= mask>>8; mask |= mask>>16;
    unsigned v = next() & mask;
    while (v > mx) v = next() & mask;
    return v;
  }
};

static void build_tab(TabArg* t) {
  HostMT rng; rng.seed(0u);
  for (int row = 0; row < 62; ++row) {
    int i = row + 1;
    bool fix[64] = {};
    fix[0] = true; fix[63] = true; fix[i-1] = true; fix[i] = true; fix[i+1] = true;
    int fixed[5]; int nf = 0; int allowed[64]; int na = 0;
    for (int b = 0; b < 64; ++b) { if (fix[b]) fixed[nf++] = b; else allowed[na++] = b; }
    int perm[64];
    for (int j = 0; j < na; ++j) perm[j] = j;
    for (int j = na - 1; j > 0; --j) {
      unsigned kk = rng.interval((unsigned)j);
      int tmp = perm[j]; perm[j] = perm[kk]; perm[kk] = tmp;
    }
    int nb = 0;
    for (int j = 0; j < nf; ++j) t->idx[row][nb++] = (unsigned char)fixed[j];
    for (int j = 0; j < 3;  ++j) t->idx[row][nb++] = (unsigned char)allowed[perm[j]];
    t->cnt[row] = (unsigned char)nb;
    for (int j = nb; j < 8; ++j) t->idx[row][j] = 0;
  }
}

// ---------------- dtype detection ----------------
__global__ __launch_bounds__(256) void detect_kernel(const unsigned short* __restrict__ x,
                                                     int* __restrict__ flag) {
  __shared__ int cnt[256];
  int c = 0;
  for (int i = threadIdx.x; i < 8192; i += 256) {
    int e = (x[i] >> 7) & 0xFF;
    if (e >= 0xC6) c++;
  }
  cnt[threadIdx.x] = c;
  __syncthreads();
  for (int s = 128; s > 0; s >>= 1) {
    if (threadIdx.x < s) cnt[threadIdx.x] += cnt[threadIdx.x + s];
    __syncthreads();
  }
  if (threadIdx.x == 0) *flag = (cnt[0] > 32) ? 1 : 0;
}

// ---------------- convert 6 small param arrays in one dispatch ----------------
struct P6 { const void* s[6]; bf16* d[6]; int n[6]; };
__global__ __launch_bounds__(256) void cvt6_kernel(const int* __restrict__ flagp, P6 p) {
  int isf = *flagp;
  int which = blockIdx.x;
  const void* src = p.s[which];
  bf16* dst = p.d[which];
  int n = p.n[which];
  int i8 = threadIdx.x * 8;
  if (i8 >= n) return;
  bf16x8 o;
  if (isf) {
    const float* s = (const float*)src + i8;
    f32x4 a = *(const f32x4*)s;
    f32x4 b = *(const f32x4*)(s + 4);
#pragma unroll
    for (int j = 0; j < 4; ++j) { o[j] = (bf16)a[j]; o[4+j] = (bf16)b[j]; }
  } else {
    o = *(const bf16x8*)((const bf16*)src + i8);
  }
  *(bf16x8*)(dst + i8) = o;
}

// ---------------- all 6 weights: fused convert + 64x64 transpose in ONE dispatch ----------------
struct W6 { const void* in[6]; bf16* out[6]; int R[6], C[6], start[6]; };
__global__ __launch_bounds__(256) void transpose_w6_kernel(const int* __restrict__ flagp, W6 wz) {
  __shared__ __align__(16) bf16 sT[64 * 72];
  int isf = *flagp;
  int which = 0;
#pragma unroll
  for (int i = 1; i < 6; ++i) if ((int)blockIdx.x >= wz.start[i]) which = i;
  const void* in = wz.in[which];
  bf16* out = wz.out[which];
  int R = wz.R[which], C = wz.C[which];
  int bid = blockIdx.x - wz.start[which];
  int cb = C >> 6;
  int br = bid / cb, bc = bid % cb;
  int r0 = br * 64, c0 = bc * 64;
  int t = threadIdx.x;
#pragma unroll
  for (int p = 0; p < 2; ++p) {
    int cid = p * 256 + t;
    int r = cid >> 3, c = cid & 7;
    bf16x8 v;
    if (isf) {
      const float* s = (const float*)in + (size_t)(r0 + r) * C + c0 + c * 8;
      f32x4 a = *(const f32x4*)s;
      f32x4 b = *(const f32x4*)(s + 4);
#pragma unroll
      for (int j = 0; j < 4; ++j) { v[j] = (bf16)a[j]; v[4+j] = (bf16)b[j]; }
    } else {
      v = *(const bf16x8*)((const bf16*)in + (size_t)(r0 + r) * C + c0 + c * 8);
    }
    *(bf16x8*)&sT[r * 72 + c * 8] = v;
  }
  __syncthreads();
#pragma unroll
  for (int p = 0; p < 2; ++p) {
    int cid = p * 256 + t;
    int oc = cid >> 3, rc = cid & 7;
    bf16x8 vv;
#pragma unroll
    for (int i = 0; i < 8; ++i) vv[i] = sT[(rc * 8 + i) * 72 + oc];
    *(bf16x8*)&out[(size_t)(c0 + oc) * R + r0 + rc * 8] = vv;
  }
}

// ---------------- LayerNorm over raw (flag-dispatched) input ----------------
__global__ __launch_bounds__(256) void ln_any_kernel(const int* __restrict__ flagp,
                                                     const void* __restrict__ x,
                                                     const bf16* __restrict__ sc,
                                                     const bf16* __restrict__ bi,
                                                     bf16* __restrict__ out) {
  int isf = *flagp;
  int row  = blockIdx.x * 4 + (threadIdx.x >> 6);
  int lane = threadIdx.x & 63;
  float f[8];
  if (isf) {
    const float* xf = (const float*)x + (size_t)row * 512 + lane * 8;
    f32x4 a = *(const f32x4*)xf;
    f32x4 b = *(const f32x4*)(xf + 4);
#pragma unroll
    for (int j = 0; j < 4; ++j) { f[j] = a[j]; f[4+j] = b[j]; }
  } else {
    bf16x8 v = ((const bf16x8*)((const bf16*)x + (size_t)row * 512))[lane];
#pragma unroll
    for (int j = 0; j < 8; ++j) f[j] = (float)v[j];
  }
  float s = 0.f, s2 = 0.f;
#pragma unroll
  for (int i = 0; i < 8; ++i) { s += f[i]; s2 += f[i]*f[i]; }
#pragma unroll
  for (int o = 32; o > 0; o >>= 1) { s += __shfl_xor(s, o, 64); s2 += __shfl_xor(s2, o, 64); }
  float mu  = s  * (1.f/512.f);
  float var = s2 * (1.f/512.f) - mu*mu;
  float rs  = rsqrtf(fmaxf(var, 0.f) + 1e-6f);
  bf16x8 sv = ((const bf16x8*)sc)[lane];
  bf16x8 bv = ((const bf16x8*)bi)[lane];
  bf16x8 o8;
#pragma unroll
  for (int i = 0; i < 8; ++i) o8[i] = (bf16)((f[i]-mu)*rs*(float)sv[i] + (float)bv[i]);
  ((bf16x8*)(out + (size_t)row * 512))[lane] = o8;
}

// ---------------- LayerNorm (bf16) ----------------
__global__ __launch_bounds__(256) void ln_bf16_kernel(const bf16* __restrict__ x,
                                                      const bf16* __restrict__ sc,
                                                      const bf16* __restrict__ bi,
                                                      bf16* __restrict__ out) {
  int row  = blockIdx.x * 4 + (threadIdx.x >> 6);
  int lane = threadIdx.x & 63;
  bf16x8 v = ((const bf16x8*)(x + (size_t)row * 512))[lane];
  float f[8], s = 0.f, s2 = 0.f;
#pragma unroll
  for (int i = 0; i < 8; ++i) { f[i] = (float)v[i]; s += f[i]; s2 += f[i]*f[i]; }
#pragma unroll
  for (int o = 32; o > 0; o >>= 1) { s += __shfl_xor(s, o, 64); s2 += __shfl_xor(s2, o, 64); }
  float mu  = s  * (1.f/512.f);
  float var = s2 * (1.f/512.f) - mu*mu;
  float rs  = rsqrtf(fmaxf(var, 0.f) + 1e-6f);
  bf16x8 sv = ((const bf16x8*)sc)[lane];
  bf16x8 bv = ((const bf16x8*)bi)[lane];
  bf16x8 o8;
#pragma unroll
  for (int i = 0; i < 8; ++i) o8[i] = (bf16)((f[i]-mu)*rs*(float)sv[i] + (float)bv[i]);
  ((bf16x8*)(out + (size_t)row * 512))[lane] = o8;
}

// ---------------- v [b,s,h,dh] -> vT [b,h,dh,s] ----------------
__global__ __launch_bounds__(256) void transpose_v_kernel(const bf16* __restrict__ v,
                                                          bf16* __restrict__ vT) {
  __shared__ __align__(16) bf16 sT[64 * 72];
  int st = blockIdx.x & 63;
  int h  = (blockIdx.x >> 6) & 7;
  int b  = blockIdx.x >> 9;
  int s0 = st * 64;
  int t  = threadIdx.x;
  const size_t ibase = ((size_t)b * 4096) * 512 + h * 64;
#pragma unroll
  for (int p = 0; p < 2; ++p) {
    int cid = p * 256 + t;
    int r = cid >> 3, c = cid & 7;
    *(bf16x8*)&sT[r * 72 + c * 8] = *(const bf16x8*)&v[ibase + (size_t)(s0 + r) * 512 + c * 8];
  }
  __syncthreads();
  const size_t obase = ((size_t)(b * 8 + h) * 64) * 4096;
#pragma unroll
  for (int p = 0; p < 2; ++p) {
    int cid = p * 256 + t;
    int dh = cid >> 3, scn = cid & 7;
    bf16x8 vv;
#pragma unroll
    for (int i = 0; i < 8; ++i) vv[i] = sT[(scn * 8 + i) * 72 + dh];
    *(bf16x8*)&vT[obase + (size_t)dh * 4096 + s0 + scn * 8] = vv;
  }
}

// ---------------- 128x128 bf16 MFMA GEMM, BK=32, double-buffered (32 KB LDS) ----------------
// grid = (M/128)*nbn blocks (1-D), M/128 divisible by 8; XCD swizzle: bid&7 -> m-strip group.
// 1 barrier per k-iter; 5 blocks/CU resident (LDS 32 KB, VGPR ~88) for cross-block overlap.
// epi 1: bf16 gout = acc + resid(f32|bf16 per flag)     (WO + residual)
// epi 2: bf16 gout = gelu_fast(acc + bias)              (FFN1)
// epi 3: (f32|bf16) gout[gout_off+i] = acc+bias+resid   (FFN2 final; resid bf16)
// epi 5: QKV split: col<512 -> gout (x0.125), <1024 -> out2, else out3; all [row][512]
__global__ __launch_bounds__(256) void gemm_kernel(const bf16* __restrict__ A,
                                                   const bf16* __restrict__ BT,
                                                   int N, int K, int nbn,
                                                   int epi,
                                                   const bf16* __restrict__ bias,
                                                   const void* __restrict__ resid,
                                                   void* __restrict__ gout,
                                                   bf16* __restrict__ out2,
                                                   bf16* __restrict__ out3,
                                                   size_t gout_off,
                                                   const int* __restrict__ flagp) {
  __shared__ __align__(16) bf16 As[2][128 * 32];
  __shared__ __align__(16) bf16 Bs[2][128 * 32];
  const int t = threadIdx.x;
  const int w = t >> 6, l = t & 63, quad = l >> 4, l15 = l & 15;
  const int wm = w >> 1, wn = w & 1;
  const int xcd = blockIdx.x & 7, g = blockIdx.x >> 3;
  const int m0 = (xcd + (g / nbn) * 8) * 128;
  const int n0 = (g % nbn) * 128;
  const int isf = (epi == 1 || epi == 3) ? *flagp : 0;
  f32x4 acc[4][4] = {};
  const int nk = K >> 5;

  // prologue: stage tile 0 into buffer 0
#pragma unroll
  for (int p = 0; p < 2; ++p) {
    int cid = p * 256 + t;
    int r = cid >> 2, c = cid & 3;
    int sc_ = c ^ (r & 3);
    gl2lds16(A  + (size_t)(m0 + r) * K + sc_ * 8, (char*)As[0] + cid * 16);
    gl2lds16(BT + (size_t)(n0 + r) * K + sc_ * 8, (char*)Bs[0] + cid * 16);
  }

  for (int kt = 0; kt < nk; ++kt) {
    __syncthreads();   // stage(kt) visible; all waves done reading buffer (kt+1)&1
    int nb = (kt + 1) & 1, cb = kt & 1;
    if (kt + 1 < nk) {
#pragma unroll
      for (int p = 0; p < 2; ++p) {
        int cid = p * 256 + t;
        int r = cid >> 2, c = cid & 3;
        int sc_ = c ^ (r & 3);
        gl2lds16(A  + (size_t)(m0 + r) * K + (kt + 1) * 32 + sc_ * 8, (char*)As[nb] + cid * 16);
        gl2lds16(BT + (size_t)(n0 + r) * K + (kt + 1) * 32 + sc_ * 8, (char*)Bs[nb] + cid * 16);
      }
    }
    bf16x8 af[4], bfr[4];
#pragma unroll
    for (int mt = 0; mt < 4; ++mt) {
      int r = wm * 64 + mt * 16 + l15;
      af[mt] = *(const bf16x8*)&As[cb][r * 32 + ((quad ^ (r & 3)) << 3)];
    }
#pragma unroll
    for (int nt = 0; nt < 4; ++nt) {
      int r = wn * 64 + nt * 16 + l15;
      bfr[nt] = *(const bf16x8*)&Bs[cb][r * 32 + ((quad ^ (r & 3)) << 3)];
    }
#pragma unroll
    for (int mt = 0; mt < 4; ++mt)
#pragma unroll
      for (int nt = 0; nt < 4; ++nt)
        acc[mt][nt] = __builtin_amdgcn_mfma_f32_16x16x32_bf16(af[mt], bfr[nt], acc[mt][nt], 0, 0, 0);
  }

  // direct-store epilogue
#pragma unroll
  for (int mt = 0; mt < 4; ++mt) {
    int rowb = m0 + wm * 64 + mt * 16 + quad * 4;
#pragma unroll
    for (int nt = 0; nt < 4; ++nt) {
      int col = n0 + wn * 64 + nt * 16 + l15;
#pragma unroll
      for (int r = 0; r < 4; ++r) {
        int row = rowb + r;
        float vacc = acc[mt][nt][r];
        size_t oidx = (size_t)row * N + col;
        if (epi == 5) {
          int which = col >> 9, c2 = col & 511;
          bf16 ov = (bf16)(which == 0 ? vacc * 0.125f : vacc);
          bf16* dst = which == 0 ? (bf16*)gout : (which == 1 ? out2 : out3);
          dst[(size_t)row * 512 + c2] = ov;
        } else if (epi == 1) {
          ((bf16*)gout)[oidx] = (bf16)(vacc + loadf(resid, oidx, isf));
        } else if (epi == 2) {
          ((bf16*)gout)[oidx] = (bf16)gelu_fast(vacc + (float)bias[col]);
        } else {
          float v = vacc + (float)bias[col] + (float)((const bf16*)resid)[oidx];
          if (isf) ((float*)gout)[gout_off + oidx] = v;
          else     ((bf16*)gout)[gout_off + oidx] = (bf16)v;
        }
      }
    }
  }
}

// ---------------- BigBird flash attention, wave-local softmax, unified dispatch ----------------
// bid < 1984: interior rows (XCD-swizzled); bid >= 1984: global rows in 8 key-chunks -> partials.
__global__ __launch_bounds__(256) void attn_kernel(TabArg targ,
                                                   const bf16* __restrict__ q,
                                                   const bf16* __restrict__ k,
                                                   const bf16* __restrict__ vT,
                                                   bf16* __restrict__ o,
                                                   float* __restrict__ part) {
  __shared__ __align__(16) bf16 sQ[64 * 64];
  __shared__ __align__(16) bf16 sK[64 * 64];
  __shared__ __align__(16) bf16 sV[64 * 64];
  __shared__ __align__(16) bf16 sP[64 * 64];

  const int t = threadIdx.x;
  const int w = t >> 6, l = t & 63, quad = l >> 4, l15 = l & 15;
  const int bid = blockIdx.x;
  int n, bh, chunk = 0, niter, mode;
  if (bid < 1984) {
    mode = 0;
    int xcd = bid & 7, g = bid >> 3;
    int bhloc = g / 62;
    n  = 1 + g % 62;
    bh = xcd + bhloc * 8;
    niter = (int)targ.cnt[n - 1];
  } else {
    mode = 1;
    int b2 = bid - 1984;
    chunk = b2 & 7;
    int gg = (b2 >> 3) & 1;
    bh = b2 >> 4;
    n = gg ? 63 : 0;
    niter = 8;
  }
  const int b = bh >> 3, h = bh & 7;
  const size_t bh_qk = ((size_t)b * 4096) * 512 + h * 64;
  const size_t bh_v  = ((size_t)(b * 8 + h) * 64) * 4096;

#pragma unroll
  for (int p = 0; p < 2; ++p) {
    int cid = p * 256 + t;
    int r = cid >> 3, c = cid & 7;
    int sc_ = c ^ (r & 7);
    gl2lds16(q + bh_qk + (size_t)(n * 64 + r) * 512 + sc_ * 8, (char*)sQ + cid * 16);
  }

  float m_r[4], l_r[4];
#pragma unroll
  for (int r = 0; r < 4; ++r) { m_r[r] = -1e30f; l_r[r] = 0.f; }
  f32x4 accO[4] = {};

  for (int it = 0; it < niter; ++it) {
    int kb = (mode == 0) ? (int)targ.idx[n - 1][it] : chunk * 8 + it;
    __syncthreads();
#pragma unroll
    for (int p = 0; p < 2; ++p) {
      int cid = p * 256 + t;
      int r = cid >> 3, c = cid & 7;
      int sc_ = c ^ (r & 7);
      gl2lds16(k  + bh_qk + (size_t)(kb * 64 + r) * 512 + sc_ * 8, (char*)sK + cid * 16);
      gl2lds16(vT + bh_v  + (size_t)r * 4096 + kb * 64 + sc_ * 8,  (char*)sV + cid * 16);
    }
    __syncthreads();

    f32x4 accS[4] = {};
#pragma unroll
    for (int ks = 0; ks < 2; ++ks) {
      int rQ = w * 16 + l15;
      int cc = ks * 4 + quad;
      bf16x8 afr = *(const bf16x8*)&sQ[rQ * 64 + ((cc ^ (rQ & 7)) << 3)];
#pragma unroll
      for (int j = 0; j < 4; ++j) {
        int rK = j * 16 + l15;
        bf16x8 bfr = *(const bf16x8*)&sK[rK * 64 + ((cc ^ (rK & 7)) << 3)];
        accS[j] = __builtin_amdgcn_mfma_f32_16x16x32_bf16(afr, bfr, accS[j], 0, 0, 0);
      }
    }

    float al[4];
#pragma unroll
    for (int r = 0; r < 4; ++r) {
      float mx = fmaxf(fmaxf(accS[0][r], accS[1][r]), fmaxf(accS[2][r], accS[3][r]));
#pragma unroll
      for (int off = 1; off < 16; off <<= 1) mx = fmaxf(mx, __shfl_xor(mx, off, 64));
      float mnew = fmaxf(m_r[r], mx);
      al[r] = __expf(m_r[r] - mnew);
      m_r[r] = mnew;
      int rowp = w * 16 + quad * 4 + r;
      float ps = 0.f;
#pragma unroll
      for (int j = 0; j < 4; ++j) {
        float pv = __expf(accS[j][r] - mnew);
        ps += pv;
        int col = j * 16 + l15;
        sP[rowp * 64 + (((col >> 3) ^ (rowp & 7)) << 3) + (col & 7)] = (bf16)pv;
      }
#pragma unroll
      for (int off = 1; off < 16; off <<= 1) ps += __shfl_xor(ps, off, 64);
      l_r[r] = l_r[r] * al[r] + ps;
    }

#pragma unroll
    for (int dt = 0; dt < 4; ++dt)
#pragma unroll
      for (int r = 0; r < 4; ++r) accO[dt][r] *= al[r];
#pragma unroll
    for (int ks = 0; ks < 2; ++ks) {
      int rP = w * 16 + l15;
      int cc = ks * 4 + quad;
      bf16x8 afr = *(const bf16x8*)&sP[rP * 64 + ((cc ^ (rP & 7)) << 3)];
#pragma unroll
      for (int dt = 0; dt < 4; ++dt) {
        int rV = dt * 16 + l15;
        bf16x8 bfr = *(const bf16x8*)&sV[rV * 64 + ((cc ^ (rV & 7)) << 3)];
        accO[dt] = __builtin_amdgcn_mfma_f32_16x16x32_bf16(afr, bfr, accO[dt], 0, 0, 0);
      }
    }
  }

  if (mode == 0) {
#pragma unroll
    for (int r = 0; r < 4; ++r) {
      int qr = w * 16 + quad * 4 + r;
      float linv = 1.f / fmaxf(l_r[r], 1e-30f);
      int srow = n * 64 + qr;
#pragma unroll
      for (int dt = 0; dt < 4; ++dt)
        o[bh_qk + (size_t)srow * 512 + dt * 16 + l15] = (bf16)(accO[dt][r] * linv);
    }
  } else {
    float* pb = part + (size_t)(bid - 1984) * (4096 + 128);
#pragma unroll
    for (int r = 0; r < 4; ++r) {
      int row = w * 16 + quad * 4 + r;
#pragma unroll
      for (int dt = 0; dt < 4; ++dt)
        pb[row * 64 + dt * 16 + l15] = accO[dt][r];
      if (l15 == 0) { pb[4096 + row] = m_r[r]; pb[4160 + row] = l_r[r]; }
    }
  }
}

// ---------------- merge 8 global-attention partials per (b,h,g) ----------------
__global__ __launch_bounds__(256) void merge_kernel(const float* __restrict__ part,
                                                    bf16* __restrict__ o) {
  const int SP = 4096 + 128;
  int g = blockIdx.x & 1, bh = blockIdx.x >> 1;
  int b = bh >> 3, h = bh & 7, n = g ? 63 : 0;
  int t = threadIdx.x;
  int row = t >> 2, st = t & 3;
  size_t pb0 = (size_t)(bh * 16 + g * 8) * SP;
  float mc[8], lc[8], M = -1e30f;
#pragma unroll
  for (int c = 0; c < 8; ++c) {
    mc[c] = part[pb0 + (size_t)c * SP + 4096 + row];
    lc[c] = part[pb0 + (size_t)c * SP + 4160 + row];
    M = fmaxf(M, mc[c]);
  }
  float L = 0.f;
  float sc[8];
#pragma unroll
  for (int c = 0; c < 8; ++c) { sc[c] = __expf(mc[c] - M); L += lc[c] * sc[c]; }
  float inv = 1.f / fmaxf(L, 1e-30f);
  f32x4 acc[4] = {};
#pragma unroll
  for (int c = 0; c < 8; ++c) {
    const float* Op = part + pb0 + (size_t)c * SP + row * 64 + st * 16;
    float s = sc[c];
#pragma unroll
    for (int i = 0; i < 4; ++i) {
      f32x4 v = *(const f32x4*)(Op + i * 4);
#pragma unroll
      for (int j = 0; j < 4; ++j) acc[i][j] += v[j] * s;
    }
  }
  size_t obase = ((size_t)b * 4096 + n * 64 + row) * 512 + h * 64 + st * 16;
#pragma unroll
  for (int i = 0; i < 4; ++i)
#pragma unroll
    for (int j = 0; j < 4; ++j)
      o[obase + i * 4 + j] = (bf16)(acc[i][j] * inv);
}

// ---------------- launch ----------------
extern "C" void kernel_launch(void* const* d_in, const int* in_sizes, int n_in,
                              void* d_out, int out_size, void* d_ws, size_t ws_size,
                              hipStream_t stream) {
  (void)in_sizes; (void)n_in; (void)out_size;
  const void* inputs = d_in[0];
  const void* ln1s = d_in[1];
  const void* ln1b = d_in[2];
  const void* wq   = d_in[3];
  const void* wk   = d_in[4];
  const void* wv   = d_in[5];
  const void* wo   = d_in[6];
  const void* ln2s = d_in[7];
  const void* ln2b = d_in[8];
  const void* w1   = d_in[9];
  const void* b1   = d_in[10];
  const void* w2   = d_in[11];
  const void* b2   = d_in[12];

  TabArg tab;
  build_tab(&tab);

  char* ws = (char*)d_ws;
  size_t off = 0;
  auto alloc = [&](size_t bytes) -> char* {
    char* p = ws + off; off += (bytes + 255) & ~(size_t)255; return p;
  };
  int*  flag   = (int*)alloc(256);
  bf16* ln1s_c = (bf16*)alloc(512 * 2);
  bf16* ln1b_c = (bf16*)alloc(512 * 2);
  bf16* ln2s_c = (bf16*)alloc(512 * 2);
  bf16* ln2b_c = (bf16*)alloc(512 * 2);
  bf16* b1_c   = (bf16*)alloc(2048 * 2);
  bf16* b2_c   = (bf16*)alloc(512 * 2);
  bf16* wqkvT  = (bf16*)alloc(1536ull * 512 * 2);
  bf16* woT    = (bf16*)alloc(512ull * 512 * 2);
  bf16* w1T    = (bf16*)alloc(512ull * 2048 * 2);
  bf16* w2T    = (bf16*)alloc(2048ull * 512 * 2);
  const size_t SZ = 16384ull * 512 * 2;
  bf16* regA = (bf16*)alloc(SZ);   // xln -> vT -> xbuf
  bf16* regB = (bf16*)alloc(SZ);   // qb  -> yln
  bf16* regC = (bf16*)alloc(SZ);   // kb  -> h1 chunk
  bf16* regD = (bf16*)alloc(SZ);   // vb  -> obuf
  size_t base_need = off;
  const size_t H1_BYTES = 16384ull * 2048 * 2;
  bool full_ffn = (ws_size >= base_need + H1_BYTES + 256);
  bf16* h1f = full_ffn ? (bf16*)alloc(H1_BYTES) : nullptr;

  bf16* xln  = regA;
  bf16* qb   = regB;
  bf16* kb   = regC;
  bf16* vb   = regD;
  bf16* vTb  = regA;
  bf16* obuf = regD;
  bf16* xbuf = regA;
  bf16* yln  = regB;
  bf16* h1c  = regC;
  float* part = (float*)d_out;   // d_out is free scratch until FFN2 writes it

  detect_kernel<<<1, 256, 0, stream>>>((const unsigned short*)inputs, flag);

  P6 p6;
  p6.s[0]=ln1s; p6.s[1]=ln1b; p6.s[2]=ln2s; p6.s[3]=ln2b; p6.s[4]=b1; p6.s[5]=b2;
  p6.d[0]=ln1s_c; p6.d[1]=ln1b_c; p6.d[2]=ln2s_c; p6.d[3]=ln2b_c; p6.d[4]=b1_c; p6.d[5]=b2_c;
  p6.n[0]=512; p6.n[1]=512; p6.n[2]=512; p6.n[3]=512; p6.n[4]=2048; p6.n[5]=512;
  cvt6_kernel<<<6, 256, 0, stream>>>(flag, p6);

  W6 w6;
  w6.in[0]=wq; w6.in[1]=wk; w6.in[2]=wv; w6.in[3]=wo; w6.in[4]=w1; w6.in[5]=w2;
  w6.out[0]=wqkvT; w6.out[1]=wqkvT+512ull*512; w6.out[2]=wqkvT+1024ull*512;
  w6.out[3]=woT; w6.out[4]=w1T; w6.out[5]=w2T;
  w6.R[0]=512; w6.R[1]=512; w6.R[2]=512; w6.R[3]=512; w6.R[4]=512;  w6.R[5]=2048;
  w6.C[0]=512; w6.C[1]=512; w6.C[2]=512; w6.C[3]=512; w6.C[4]=2048; w6.C[5]=512;
  w6.start[0]=0; w6.start[1]=64; w6.start[2]=128; w6.start[3]=192; w6.start[4]=256; w6.start[5]=512;
  transpose_w6_kernel<<<768, 256, 0, stream>>>(flag, w6);

  ln_any_kernel<<<4096, 256, 0, stream>>>(flag, inputs, ln1s_c, ln1b_c, xln);

  // fused QKV: N=1536 (nbn=12)
  gemm_kernel<<<128 * 12, 256, 0, stream>>>(xln, wqkvT, 1536, 512, 12, 5,
                                            nullptr, nullptr, qb, kb, vb, 0, flag);

  transpose_v_kernel<<<2048, 256, 0, stream>>>(vb, vTb);

  attn_kernel<<<2496, 256, 0, stream>>>(tab, qb, kb, vTb, obuf, part);
  merge_kernel<<<64,  256, 0, stream>>>(part, obuf);

  gemm_kernel<<<128 * 4, 256, 0, stream>>>(obuf, woT, 512, 512, 4, 1,
                                           nullptr, inputs, xbuf, nullptr, nullptr, 0, flag);

  ln_bf16_kernel<<<4096, 256, 0, stream>>>(xbuf, ln2s_c, ln2b_c, yln);

  if (full_ffn) {
    gemm_kernel<<<128 * 16, 256, 0, stream>>>(yln, w1T, 2048, 512, 16, 2,
                                              b1_c, nullptr, h1f, nullptr, nullptr, 0, flag);
    gemm_kernel<<<128 * 4, 256, 0, stream>>>(h1f, w2T, 512, 2048, 4, 3,
                                             b2_c, xbuf, d_out, nullptr, nullptr, 0, flag);
  } else {
    for (int c = 0; c < 4; ++c) {
      const bf16* yc = yln  + (size_t)c * 4096 * 512;
      const bf16* xc = xbuf + (size_t)c * 4096 * 512;
      size_t oo = (size_t)c * 4096 * 512;
      gemm_kernel<<<32 * 16, 256, 0, stream>>>(yc, w1T, 2048, 512, 16, 2,
                                               b1_c, nullptr, h1c, nullptr, nullptr, 0, flag);
      gemm_kernel<<<32 * 4, 256, 0, stream>>>(h1c, w2T, 512, 2048, 4, 3,
                                              b2_c, xc, d_out, nullptr, nullptr, oo, flag);
    }
  }
}